// Round 6
// baseline (292.070 us; speedup 1.0000x reference)
//
#include <hip/hip_runtime.h>
#include <hip/hip_bf16.h>
#include <hip/hip_fp16.h>

// GraphSAGE edge classifier.
// v5b — fp16 gather intermediates (L2-resident working sets) + nt output stores.
//  K1 bincount : per-(block,bucket) histogram of dst buckets
//  K2a scan1   : per-bucket local exclusive scan of its 512 chunk-counts + total
//  K2b scan2   : single-block exclusive scan of 196 bucket totals -> bstart
//  K3 binwrite : packed (dst_local<<17|src) entries into exclusive bucket ranges
//  K3b sort    : per-bucket LDS counting sort (in-place) -> srclist + row_csr
//  K4 lin1     : yh = half(x@W1l), z = x@W1r
//  K5 agg1     : CSR gather mean(yh) -> h1=relu(+b1+z) -> ph=half(h1@W2l), q=h1@W2r
//  K6 agg2     : CSR gather mean(ph) -> h2=relu(+b2+q) -> Uh,Vh (half)
//  K7 edge_out : out = log_softmax(Uh[src] + Vh[dst] + bc)   (nt stores)

#define NBLK 512
#define BUCKET_BITS 9
#define BUCKET_SZ 512
#define MAXNB 256
#define STAGE_CAP 36000

struct __align__(16) H8 { __half2 a, b, c, d; };
typedef float f32x4 __attribute__((ext_vector_type(4)));

__global__ __launch_bounds__(512) void bincount_kernel(const int* __restrict__ ei,
                                                       int* __restrict__ counts,
                                                       int E, int NB, int chunk) {
  __shared__ int hist[MAXNB];
  for (int i = threadIdx.x; i < NB; i += 512) hist[i] = 0;
  __syncthreads();
  int s = blockIdx.x * chunk;
  int eend = s + chunk; if (eend > E) eend = E;
  for (int e = s + threadIdx.x; e < eend; e += 512)
    atomicAdd(&hist[ei[E + e] >> BUCKET_BITS], 1);
  __syncthreads();
  for (int b = threadIdx.x; b < NB; b += 512)
    counts[b * NBLK + blockIdx.x] = hist[b];
}

__global__ __launch_bounds__(512) void scan1_kernel(const int* __restrict__ counts,
                                                    int* __restrict__ locoff,
                                                    int* __restrict__ total) {
  __shared__ int wsum[8];
  int b = blockIdx.x;
  int t = threadIdx.x;
  int lane = t & 63, wid = t >> 6;
  int v = counts[b * NBLK + t];
  int incl = v;
#pragma unroll
  for (int d = 1; d < 64; d <<= 1) {
    int u = __shfl_up(incl, d);
    if (lane >= d) incl += u;
  }
  if (lane == 63) wsum[wid] = incl;
  __syncthreads();
  if (t < 64) {
    int w = (t < 8) ? wsum[t] : 0;
#pragma unroll
    for (int d = 1; d < 8; d <<= 1) {
      int u = __shfl_up(w, d);
      if (lane >= d) w += u;
    }
    if (t < 8) wsum[t] = w;
  }
  __syncthreads();
  int excl = ((wid > 0) ? wsum[wid - 1] : 0) + (incl - v);
  locoff[b * NBLK + t] = excl;
  if (t == NBLK - 1) total[b] = excl + v;
}

__global__ __launch_bounds__(256) void scan2_kernel(const int* __restrict__ total,
                                                    int* __restrict__ bstart, int NB) {
  __shared__ int wsum[4];
  int t = threadIdx.x;
  int lane = t & 63, wid = t >> 6;
  int v = (t < NB) ? total[t] : 0;
  int incl = v;
#pragma unroll
  for (int d = 1; d < 64; d <<= 1) {
    int u = __shfl_up(incl, d);
    if (lane >= d) incl += u;
  }
  if (lane == 63) wsum[wid] = incl;
  __syncthreads();
  if (t < 64) {
    int w = (t < 4) ? wsum[t] : 0;
#pragma unroll
    for (int d = 1; d < 4; d <<= 1) {
      int u = __shfl_up(w, d);
      if (lane >= d) w += u;
    }
    if (t < 4) wsum[t] = w;
  }
  __syncthreads();
  int excl = ((wid > 0) ? wsum[wid - 1] : 0) + (incl - v);
  if (t <= NB) bstart[t] = excl;
}

__global__ __launch_bounds__(512) void binwrite_kernel(const int* __restrict__ ei,
                                                       const int* __restrict__ locoff,
                                                       const int* __restrict__ bstart,
                                                       int* __restrict__ elist,
                                                       int E, int NB, int chunk) {
  __shared__ int cur[MAXNB];
  for (int b = threadIdx.x; b < NB; b += 512)
    cur[b] = bstart[b] + locoff[b * NBLK + blockIdx.x];
  __syncthreads();
  int s = blockIdx.x * chunk;
  int eend = s + chunk; if (eend > E) eend = E;
  for (int e = s + threadIdx.x; e < eend; e += 512) {
    int src = ei[e];
    int dst = ei[E + e];
    int b = dst >> BUCKET_BITS;
    int pos = atomicAdd(&cur[b], 1);
    elist[pos] = ((dst & (BUCKET_SZ - 1)) << 17) | src;
  }
}

__global__ __launch_bounds__(1024) void sort_kernel(int* __restrict__ elist,
                                                    const int* __restrict__ bstart,
                                                    int* __restrict__ row_csr,
                                                    int N) {
  extern __shared__ int sm[];
  int* stage = sm;
  int* hist  = sm + STAGE_CAP;
  int* wtmp  = hist + 512;
  int t = threadIdx.x;
  int b = blockIdx.x;
  int beg = bstart[b];
  int end = bstart[b + 1];
  int cnt = end - beg;
  if (cnt > STAGE_CAP) cnt = STAGE_CAP;
  for (int i = t; i < cnt; i += 1024) stage[i] = elist[beg + i];
  if (t < 512) hist[t] = 0;
  __syncthreads();
  for (int i = t; i < cnt; i += 1024)
    atomicAdd(&hist[((unsigned)stage[i]) >> 17], 1);
  __syncthreads();
  int lane = t & 63;
  int wv = t >> 6;
  int v = (t < 512) ? hist[t] : 0;
  int incl = v;
#pragma unroll
  for (int d = 1; d < 64; d <<= 1) {
    int u = __shfl_up(incl, d);
    if (lane >= d) incl += u;
  }
  if (t < 512 && lane == 63) wtmp[wv] = incl;
  __syncthreads();
  if (t < 64) {
    int w = (t < 8) ? wtmp[t] : 0;
#pragma unroll
    for (int d = 1; d < 8; d <<= 1) {
      int u = __shfl_up(w, d);
      if (lane >= d) w += u;
    }
    if (t < 8) wtmp[t] = w;
  }
  __syncthreads();
  if (t < 512) {
    int excl = ((wv > 0) ? wtmp[wv - 1] : 0) + (incl - v);
    hist[t] = excl;
    int node = (b << BUCKET_BITS) + t;
    if (node <= N) row_csr[node] = beg + excl;
  }
  __syncthreads();
  for (int i = t; i < cnt; i += 1024) {
    unsigned ent = (unsigned)stage[i];
    int pos = atomicAdd(&hist[ent >> 17], 1);
    elist[beg + pos] = ent & 0x1FFFF;
  }
}

// yh = half(x@W1l), z = x@W1r ; 32 nodes per 256-thread block
__global__ __launch_bounds__(256) void lin1_kernel(const float* __restrict__ x,
                                                   const float* __restrict__ W1l,
                                                   const float* __restrict__ W1r,
                                                   __half* __restrict__ yh,
                                                   float* __restrict__ z, int N) {
  __shared__ float Xs[32 * 129];
  __shared__ float Ws[128 * 32];
  int t = threadIdx.x;
  for (int i = t; i < 128 * 16; i += 256) {
    int k = i >> 4, c = i & 15;
    Ws[k * 32 + c] = W1l[i];
    Ws[k * 32 + 16 + c] = W1r[i];
  }
  int nb = blockIdx.x * 32;
  const float4* xg = (const float4*)(x + (size_t)nb * 128);
  for (int i4 = t; i4 < 32 * 32; i4 += 256) {
    float4 val = xg[i4];
    int r = i4 >> 5, c4 = (i4 & 31) * 4;
    float* dp = &Xs[r * 129 + c4];
    dp[0] = val.x; dp[1] = val.y; dp[2] = val.z; dp[3] = val.w;
  }
  __syncthreads();
  int n = t & 31, cg = t >> 5;
  float a0 = 0.f, a1 = 0.f, a2 = 0.f, a3 = 0.f;
  for (int k = 0; k < 128; ++k) {
    float xv = Xs[n * 129 + k];
    const float* wr = &Ws[k * 32 + cg * 4];
    a0 += xv * wr[0]; a1 += xv * wr[1]; a2 += xv * wr[2]; a3 += xv * wr[3];
  }
  int node = nb + n;
  if (node < N) {
    int c = cg * 4;
    if (c < 16) {
      __half2* yp = (__half2*)(yh + (size_t)node * 16 + c);
      yp[0] = __floats2half2_rn(a0, a1);
      yp[1] = __floats2half2_rn(a2, a3);
    } else {
      float* op = z + (size_t)node * 16 + (c - 16);
      op[0] = a0; op[1] = a1; op[2] = a2; op[3] = a3;
    }
  }
}

// CSR gather mean(yh) -> h=relu(+b1+z) -> ph=half(h@W2l), q=h@W2r ; 16 lanes/node
__global__ __launch_bounds__(256) void agg1_kernel(const __half* __restrict__ yh,
                                                   const float* __restrict__ z,
                                                   const int* __restrict__ row_csr,
                                                   const int* __restrict__ srclist,
                                                   const float* __restrict__ b1,
                                                   const float* __restrict__ W2l,
                                                   const float* __restrict__ W2r,
                                                   __half* __restrict__ ph,
                                                   float* __restrict__ q, int N) {
  int g = (blockIdx.x * 256 + threadIdx.x) >> 4;
  int k = threadIdx.x & 15;
  if (g >= N) return;
  int beg = row_csr[g], end = row_csr[g + 1];
  float acc = 0.f;
  int j = beg;
  for (; j + 4 <= end; j += 4) {
    int s0 = srclist[j], s1 = srclist[j + 1];
    int s2 = srclist[j + 2], s3 = srclist[j + 3];
    acc += __half2float(yh[(size_t)s0 * 16 + k]);
    acc += __half2float(yh[(size_t)s1 * 16 + k]);
    acc += __half2float(yh[(size_t)s2 * 16 + k]);
    acc += __half2float(yh[(size_t)s3 * 16 + k]);
  }
  for (; j < end; ++j) acc += __half2float(yh[(size_t)srclist[j] * 16 + k]);
  int deg = end - beg;
  float mean = acc / (float)(deg > 0 ? deg : 1);
  float h = fmaxf(mean + b1[k] + z[(size_t)g * 16 + k], 0.f);
  float pa = 0.f, qa = 0.f;
#pragma unroll
  for (int kk = 0; kk < 16; ++kk) {
    float hk = __shfl(h, kk, 16);
    pa += hk * W2l[kk * 16 + k];
    qa += hk * W2r[kk * 16 + k];
  }
  ph[(size_t)g * 16 + k] = __float2half(pa);
  q[(size_t)g * 16 + k] = qa;
}

// CSR gather mean(ph) -> h=relu(+b2+q) -> Uh=half(h@Wc[:16]), Vh=half(h@Wc[16:])
__global__ __launch_bounds__(256) void agg2_kernel(const __half* __restrict__ ph,
                                                   const float* __restrict__ q,
                                                   const int* __restrict__ row_csr,
                                                   const int* __restrict__ srclist,
                                                   const float* __restrict__ b2,
                                                   const float* __restrict__ Wc,
                                                   __half* __restrict__ Uh,
                                                   __half* __restrict__ Vh, int N) {
  int g = (blockIdx.x * 256 + threadIdx.x) >> 4;
  int k = threadIdx.x & 15;
  if (g >= N) return;
  int beg = row_csr[g], end = row_csr[g + 1];
  float acc = 0.f;
  int j = beg;
  for (; j + 4 <= end; j += 4) {
    int s0 = srclist[j], s1 = srclist[j + 1];
    int s2 = srclist[j + 2], s3 = srclist[j + 3];
    acc += __half2float(ph[(size_t)s0 * 16 + k]);
    acc += __half2float(ph[(size_t)s1 * 16 + k]);
    acc += __half2float(ph[(size_t)s2 * 16 + k]);
    acc += __half2float(ph[(size_t)s3 * 16 + k]);
  }
  for (; j < end; ++j) acc += __half2float(ph[(size_t)srclist[j] * 16 + k]);
  int deg = end - beg;
  float mean = acc / (float)(deg > 0 ? deg : 1);
  float h = fmaxf(mean + b2[k] + q[(size_t)g * 16 + k], 0.f);
  int wbase = (k < 8) ? 0 : 16;
  int c = k & 7;
  float o = 0.f;
#pragma unroll
  for (int kk = 0; kk < 16; ++kk) {
    float hk = __shfl(h, kk, 16);
    o += hk * Wc[(wbase + kk) * 8 + c];
  }
  if (k < 8) Uh[(size_t)g * 8 + c] = __float2half(o);
  else       Vh[(size_t)g * 8 + c] = __float2half(o);
}

// 2 edges per thread; fp16 gathers (L2-resident); nt fp32 output stores
__global__ __launch_bounds__(256) void edge_out_kernel(const int* __restrict__ ei,
                                                       const __half* __restrict__ Uh,
                                                       const __half* __restrict__ Vh,
                                                       const float* __restrict__ bc,
                                                       float* __restrict__ out, int E) {
  int e0 = (blockIdx.x * 256 + threadIdx.x) * 2;
  float bcv[8];
  {
    float4 c0 = ((const float4*)bc)[0], c1 = ((const float4*)bc)[1];
    bcv[0] = c0.x; bcv[1] = c0.y; bcv[2] = c0.z; bcv[3] = c0.w;
    bcv[4] = c1.x; bcv[5] = c1.y; bcv[6] = c1.z; bcv[7] = c1.w;
  }
#pragma unroll
  for (int ii = 0; ii < 2; ++ii) {
    int e = e0 + ii;
    if (e >= E) return;
    int src = ei[e];
    int dst = ei[E + e];
    H8 u8 = *(const H8*)(Uh + (size_t)src * 8);
    H8 v8 = *(const H8*)(Vh + (size_t)dst * 8);
    float2 ua = __half22float2(u8.a), ub = __half22float2(u8.b);
    float2 uc = __half22float2(u8.c), ud = __half22float2(u8.d);
    float2 va = __half22float2(v8.a), vb = __half22float2(v8.b);
    float2 vc = __half22float2(v8.c), vd = __half22float2(v8.d);
    float t[8];
    t[0] = ua.x + va.x + bcv[0]; t[1] = ua.y + va.y + bcv[1];
    t[2] = ub.x + vb.x + bcv[2]; t[3] = ub.y + vb.y + bcv[3];
    t[4] = uc.x + vc.x + bcv[4]; t[5] = uc.y + vc.y + bcv[5];
    t[6] = ud.x + vd.x + bcv[6]; t[7] = ud.y + vd.y + bcv[7];
    float m = t[0];
#pragma unroll
    for (int c = 1; c < 8; ++c) m = fmaxf(m, t[c]);
    float s = 0.f;
#pragma unroll
    for (int c = 0; c < 8; ++c) s += __expf(t[c] - m);
    float lse = m + __logf(s);
    f32x4 o0 = { t[0] - lse, t[1] - lse, t[2] - lse, t[3] - lse };
    f32x4 o1 = { t[4] - lse, t[5] - lse, t[6] - lse, t[7] - lse };
    f32x4* op = (f32x4*)(out + (size_t)e * 8);
    __builtin_nontemporal_store(o0, op);
    __builtin_nontemporal_store(o1, op + 1);
  }
}

extern "C" void kernel_launch(void* const* d_in, const int* in_sizes, int n_in,
                              void* d_out, int out_size, void* d_ws, size_t ws_size,
                              hipStream_t stream) {
  const float* x   = (const float*)d_in[0];
  const int*   ei  = (const int*)d_in[1];
  const float* W1l = (const float*)d_in[2];
  const float* b1  = (const float*)d_in[3];
  const float* W1r = (const float*)d_in[4];
  const float* W2l = (const float*)d_in[5];
  const float* b2  = (const float*)d_in[6];
  const float* W2r = (const float*)d_in[7];
  const float* Wc  = (const float*)d_in[8];
  const float* bc  = (const float*)d_in[9];
  float* out = (float*)d_out;

  const int N = in_sizes[0] / 128;   // 100000
  const int E = in_sizes[1] / 2;     // 3200000
  const size_t N16 = (size_t)N * 16;
  const int NB = (N + BUCKET_SZ - 1) >> BUCKET_BITS;   // 196
  const int chunk = (E + NBLK - 1) / NBLK;

  // Workspace layout
  __half* yh = (__half*)d_ws;            // N*16 half
  __half* ph = yh + N16;                 // N*16 half
  __half* Uh = ph + N16;                 // N*8 half
  __half* Vh = Uh + (size_t)N * 8;       // N*8 half
  float*  z  = (float*)(Vh + (size_t)N * 8);  // N*16 f32
  float*  q  = z + N16;                  // N*16 f32
  int* counts  = (int*)(q + N16);        // NB*NBLK
  int* locoff  = counts + NB * NBLK;     // NB*NBLK
  int* total   = locoff + NB * NBLK;     // NB
  int* bstart  = total + NB;             // NB + 1
  int* elist   = bstart + NB + 1;        // E
  int* row_csr = elist + E;              // N + 1

  bincount_kernel<<<NBLK, 512, 0, stream>>>(ei, counts, E, NB, chunk);
  scan1_kernel<<<NB, 512, 0, stream>>>(counts, locoff, total);
  scan2_kernel<<<1, 256, 0, stream>>>(total, bstart, NB);
  binwrite_kernel<<<NBLK, 512, 0, stream>>>(ei, locoff, bstart, elist, E, NB, chunk);
  size_t smem = (STAGE_CAP + 512 + 16) * sizeof(int);
  sort_kernel<<<NB, 1024, smem, stream>>>(elist, bstart, row_csr, N);

  lin1_kernel<<<(N + 31) / 32, 256, 0, stream>>>(x, W1l, W1r, yh, z, N);

  int ngrid = (N * 16 + 255) / 256;
  agg1_kernel<<<ngrid, 256, 0, stream>>>(yh, z, row_csr, elist, b1, W2l, W2r, ph, q, N);
  agg2_kernel<<<ngrid, 256, 0, stream>>>(ph, q, row_csr, elist, b2, Wc, Uh, Vh, N);

  int egrid = (E / 2 + 255) / 256;
  edge_out_kernel<<<egrid, 256, 0, stream>>>(ei, Uh, Vh, bc, out, E);
}

// Round 7
// 211.070 us; speedup vs baseline: 1.3838x; 1.3838x over previous
//
#include <hip/hip_runtime.h>
#include <hip/hip_bf16.h>
#include <hip/hip_fp16.h>

// GraphSAGE edge classifier.
// v6 — fp16 gather intermediates (L2-resident) + normal cached output stores
//      (nt stores regressed: 16B nt stores don't write-combine -> 1.45x WRITE).
//  K1 bincount : per-(block,bucket) histogram of dst buckets
//  K2a scan1   : per-bucket local exclusive scan of its 512 chunk-counts + total
//  K2b scan2   : single-block exclusive scan of 196 bucket totals -> bstart
//  K3 binwrite : packed (dst_local<<17|src) entries into exclusive bucket ranges
//  K3b sort    : per-bucket LDS counting sort (in-place) -> srclist + row_csr
//  K4 lin1     : yh = half(x@W1l), z = x@W1r
//  K5 agg1     : CSR gather mean(yh) -> h1=relu(+b1+z) -> ph=half(h1@W2l), q=h1@W2r
//  K6 agg2     : CSR gather mean(ph) -> h2=relu(+b2+q) -> Uh,Vh (half)
//  K7 edge_out : out = log_softmax(Uh[src] + Vh[dst] + bc)

#define NBLK 512
#define BUCKET_BITS 9
#define BUCKET_SZ 512
#define MAXNB 256
#define STAGE_CAP 36000

struct __align__(16) H8 { __half2 a, b, c, d; };

__global__ __launch_bounds__(512) void bincount_kernel(const int* __restrict__ ei,
                                                       int* __restrict__ counts,
                                                       int E, int NB, int chunk) {
  __shared__ int hist[MAXNB];
  for (int i = threadIdx.x; i < NB; i += 512) hist[i] = 0;
  __syncthreads();
  int s = blockIdx.x * chunk;
  int eend = s + chunk; if (eend > E) eend = E;
  for (int e = s + threadIdx.x; e < eend; e += 512)
    atomicAdd(&hist[ei[E + e] >> BUCKET_BITS], 1);
  __syncthreads();
  for (int b = threadIdx.x; b < NB; b += 512)
    counts[b * NBLK + blockIdx.x] = hist[b];
}

__global__ __launch_bounds__(512) void scan1_kernel(const int* __restrict__ counts,
                                                    int* __restrict__ locoff,
                                                    int* __restrict__ total) {
  __shared__ int wsum[8];
  int b = blockIdx.x;
  int t = threadIdx.x;
  int lane = t & 63, wid = t >> 6;
  int v = counts[b * NBLK + t];
  int incl = v;
#pragma unroll
  for (int d = 1; d < 64; d <<= 1) {
    int u = __shfl_up(incl, d);
    if (lane >= d) incl += u;
  }
  if (lane == 63) wsum[wid] = incl;
  __syncthreads();
  if (t < 64) {
    int w = (t < 8) ? wsum[t] : 0;
#pragma unroll
    for (int d = 1; d < 8; d <<= 1) {
      int u = __shfl_up(w, d);
      if (lane >= d) w += u;
    }
    if (t < 8) wsum[t] = w;
  }
  __syncthreads();
  int excl = ((wid > 0) ? wsum[wid - 1] : 0) + (incl - v);
  locoff[b * NBLK + t] = excl;
  if (t == NBLK - 1) total[b] = excl + v;
}

__global__ __launch_bounds__(256) void scan2_kernel(const int* __restrict__ total,
                                                    int* __restrict__ bstart, int NB) {
  __shared__ int wsum[4];
  int t = threadIdx.x;
  int lane = t & 63, wid = t >> 6;
  int v = (t < NB) ? total[t] : 0;
  int incl = v;
#pragma unroll
  for (int d = 1; d < 64; d <<= 1) {
    int u = __shfl_up(incl, d);
    if (lane >= d) incl += u;
  }
  if (lane == 63) wsum[wid] = incl;
  __syncthreads();
  if (t < 64) {
    int w = (t < 4) ? wsum[t] : 0;
#pragma unroll
    for (int d = 1; d < 4; d <<= 1) {
      int u = __shfl_up(w, d);
      if (lane >= d) w += u;
    }
    if (t < 4) wsum[t] = w;
  }
  __syncthreads();
  int excl = ((wid > 0) ? wsum[wid - 1] : 0) + (incl - v);
  if (t <= NB) bstart[t] = excl;
}

__global__ __launch_bounds__(512) void binwrite_kernel(const int* __restrict__ ei,
                                                       const int* __restrict__ locoff,
                                                       const int* __restrict__ bstart,
                                                       int* __restrict__ elist,
                                                       int E, int NB, int chunk) {
  __shared__ int cur[MAXNB];
  for (int b = threadIdx.x; b < NB; b += 512)
    cur[b] = bstart[b] + locoff[b * NBLK + blockIdx.x];
  __syncthreads();
  int s = blockIdx.x * chunk;
  int eend = s + chunk; if (eend > E) eend = E;
  for (int e = s + threadIdx.x; e < eend; e += 512) {
    int src = ei[e];
    int dst = ei[E + e];
    int b = dst >> BUCKET_BITS;
    int pos = atomicAdd(&cur[b], 1);
    elist[pos] = ((dst & (BUCKET_SZ - 1)) << 17) | src;
  }
}

__global__ __launch_bounds__(1024) void sort_kernel(int* __restrict__ elist,
                                                    const int* __restrict__ bstart,
                                                    int* __restrict__ row_csr,
                                                    int N) {
  extern __shared__ int sm[];
  int* stage = sm;
  int* hist  = sm + STAGE_CAP;
  int* wtmp  = hist + 512;
  int t = threadIdx.x;
  int b = blockIdx.x;
  int beg = bstart[b];
  int end = bstart[b + 1];
  int cnt = end - beg;
  if (cnt > STAGE_CAP) cnt = STAGE_CAP;
  for (int i = t; i < cnt; i += 1024) stage[i] = elist[beg + i];
  if (t < 512) hist[t] = 0;
  __syncthreads();
  for (int i = t; i < cnt; i += 1024)
    atomicAdd(&hist[((unsigned)stage[i]) >> 17], 1);
  __syncthreads();
  int lane = t & 63;
  int wv = t >> 6;
  int v = (t < 512) ? hist[t] : 0;
  int incl = v;
#pragma unroll
  for (int d = 1; d < 64; d <<= 1) {
    int u = __shfl_up(incl, d);
    if (lane >= d) incl += u;
  }
  if (t < 512 && lane == 63) wtmp[wv] = incl;
  __syncthreads();
  if (t < 64) {
    int w = (t < 8) ? wtmp[t] : 0;
#pragma unroll
    for (int d = 1; d < 8; d <<= 1) {
      int u = __shfl_up(w, d);
      if (lane >= d) w += u;
    }
    if (t < 8) wtmp[t] = w;
  }
  __syncthreads();
  if (t < 512) {
    int excl = ((wv > 0) ? wtmp[wv - 1] : 0) + (incl - v);
    hist[t] = excl;
    int node = (b << BUCKET_BITS) + t;
    if (node <= N) row_csr[node] = beg + excl;
  }
  __syncthreads();
  for (int i = t; i < cnt; i += 1024) {
    unsigned ent = (unsigned)stage[i];
    int pos = atomicAdd(&hist[ent >> 17], 1);
    elist[beg + pos] = ent & 0x1FFFF;
  }
}

// yh = half(x@W1l), z = x@W1r ; 32 nodes per 256-thread block
__global__ __launch_bounds__(256) void lin1_kernel(const float* __restrict__ x,
                                                   const float* __restrict__ W1l,
                                                   const float* __restrict__ W1r,
                                                   __half* __restrict__ yh,
                                                   float* __restrict__ z, int N) {
  __shared__ float Xs[32 * 129];
  __shared__ float Ws[128 * 32];
  int t = threadIdx.x;
  for (int i = t; i < 128 * 16; i += 256) {
    int k = i >> 4, c = i & 15;
    Ws[k * 32 + c] = W1l[i];
    Ws[k * 32 + 16 + c] = W1r[i];
  }
  int nb = blockIdx.x * 32;
  const float4* xg = (const float4*)(x + (size_t)nb * 128);
  for (int i4 = t; i4 < 32 * 32; i4 += 256) {
    float4 val = xg[i4];
    int r = i4 >> 5, c4 = (i4 & 31) * 4;
    float* dp = &Xs[r * 129 + c4];
    dp[0] = val.x; dp[1] = val.y; dp[2] = val.z; dp[3] = val.w;
  }
  __syncthreads();
  int n = t & 31, cg = t >> 5;
  float a0 = 0.f, a1 = 0.f, a2 = 0.f, a3 = 0.f;
  for (int k = 0; k < 128; ++k) {
    float xv = Xs[n * 129 + k];
    const float* wr = &Ws[k * 32 + cg * 4];
    a0 += xv * wr[0]; a1 += xv * wr[1]; a2 += xv * wr[2]; a3 += xv * wr[3];
  }
  int node = nb + n;
  if (node < N) {
    int c = cg * 4;
    if (c < 16) {
      __half2* yp = (__half2*)(yh + (size_t)node * 16 + c);
      yp[0] = __floats2half2_rn(a0, a1);
      yp[1] = __floats2half2_rn(a2, a3);
    } else {
      float* op = z + (size_t)node * 16 + (c - 16);
      op[0] = a0; op[1] = a1; op[2] = a2; op[3] = a3;
    }
  }
}

// CSR gather mean(yh) -> h=relu(+b1+z) -> ph=half(h@W2l), q=h@W2r ; 16 lanes/node
__global__ __launch_bounds__(256) void agg1_kernel(const __half* __restrict__ yh,
                                                   const float* __restrict__ z,
                                                   const int* __restrict__ row_csr,
                                                   const int* __restrict__ srclist,
                                                   const float* __restrict__ b1,
                                                   const float* __restrict__ W2l,
                                                   const float* __restrict__ W2r,
                                                   __half* __restrict__ ph,
                                                   float* __restrict__ q, int N) {
  int g = (blockIdx.x * 256 + threadIdx.x) >> 4;
  int k = threadIdx.x & 15;
  if (g >= N) return;
  int beg = row_csr[g], end = row_csr[g + 1];
  float acc = 0.f;
  int j = beg;
  for (; j + 4 <= end; j += 4) {
    int s0 = srclist[j], s1 = srclist[j + 1];
    int s2 = srclist[j + 2], s3 = srclist[j + 3];
    acc += __half2float(yh[(size_t)s0 * 16 + k]);
    acc += __half2float(yh[(size_t)s1 * 16 + k]);
    acc += __half2float(yh[(size_t)s2 * 16 + k]);
    acc += __half2float(yh[(size_t)s3 * 16 + k]);
  }
  for (; j < end; ++j) acc += __half2float(yh[(size_t)srclist[j] * 16 + k]);
  int deg = end - beg;
  float mean = acc / (float)(deg > 0 ? deg : 1);
  float h = fmaxf(mean + b1[k] + z[(size_t)g * 16 + k], 0.f);
  float pa = 0.f, qa = 0.f;
#pragma unroll
  for (int kk = 0; kk < 16; ++kk) {
    float hk = __shfl(h, kk, 16);
    pa += hk * W2l[kk * 16 + k];
    qa += hk * W2r[kk * 16 + k];
  }
  ph[(size_t)g * 16 + k] = __float2half(pa);
  q[(size_t)g * 16 + k] = qa;
}

// CSR gather mean(ph) -> h=relu(+b2+q) -> Uh=half(h@Wc[:16]), Vh=half(h@Wc[16:])
__global__ __launch_bounds__(256) void agg2_kernel(const __half* __restrict__ ph,
                                                   const float* __restrict__ q,
                                                   const int* __restrict__ row_csr,
                                                   const int* __restrict__ srclist,
                                                   const float* __restrict__ b2,
                                                   const float* __restrict__ Wc,
                                                   __half* __restrict__ Uh,
                                                   __half* __restrict__ Vh, int N) {
  int g = (blockIdx.x * 256 + threadIdx.x) >> 4;
  int k = threadIdx.x & 15;
  if (g >= N) return;
  int beg = row_csr[g], end = row_csr[g + 1];
  float acc = 0.f;
  int j = beg;
  for (; j + 4 <= end; j += 4) {
    int s0 = srclist[j], s1 = srclist[j + 1];
    int s2 = srclist[j + 2], s3 = srclist[j + 3];
    acc += __half2float(ph[(size_t)s0 * 16 + k]);
    acc += __half2float(ph[(size_t)s1 * 16 + k]);
    acc += __half2float(ph[(size_t)s2 * 16 + k]);
    acc += __half2float(ph[(size_t)s3 * 16 + k]);
  }
  for (; j < end; ++j) acc += __half2float(ph[(size_t)srclist[j] * 16 + k]);
  int deg = end - beg;
  float mean = acc / (float)(deg > 0 ? deg : 1);
  float h = fmaxf(mean + b2[k] + q[(size_t)g * 16 + k], 0.f);
  int wbase = (k < 8) ? 0 : 16;
  int c = k & 7;
  float o = 0.f;
#pragma unroll
  for (int kk = 0; kk < 16; ++kk) {
    float hk = __shfl(h, kk, 16);
    o += hk * Wc[(wbase + kk) * 8 + c];
  }
  if (k < 8) Uh[(size_t)g * 8 + c] = __float2half(o);
  else       Vh[(size_t)g * 8 + c] = __float2half(o);
}

// fp16 gathers (L2-resident); normal cached fp32 float4 output stores
__global__ __launch_bounds__(256) void edge_out_kernel(const int* __restrict__ ei,
                                                       const __half* __restrict__ Uh,
                                                       const __half* __restrict__ Vh,
                                                       const float* __restrict__ bc,
                                                       float* __restrict__ out, int E) {
  int e = blockIdx.x * 256 + threadIdx.x;
  if (e >= E) return;
  int src = ei[e];
  int dst = ei[E + e];
  H8 u8 = *(const H8*)(Uh + (size_t)src * 8);
  H8 v8 = *(const H8*)(Vh + (size_t)dst * 8);
  float4 c0 = ((const float4*)bc)[0], c1 = ((const float4*)bc)[1];
  float2 ua = __half22float2(u8.a), ub = __half22float2(u8.b);
  float2 uc = __half22float2(u8.c), ud = __half22float2(u8.d);
  float2 va = __half22float2(v8.a), vb = __half22float2(v8.b);
  float2 vc = __half22float2(v8.c), vd = __half22float2(v8.d);
  float t[8];
  t[0] = ua.x + va.x + c0.x; t[1] = ua.y + va.y + c0.y;
  t[2] = ub.x + vb.x + c0.z; t[3] = ub.y + vb.y + c0.w;
  t[4] = uc.x + vc.x + c1.x; t[5] = uc.y + vc.y + c1.y;
  t[6] = ud.x + vd.x + c1.z; t[7] = ud.y + vd.y + c1.w;
  float m = t[0];
#pragma unroll
  for (int c = 1; c < 8; ++c) m = fmaxf(m, t[c]);
  float s = 0.f;
#pragma unroll
  for (int c = 0; c < 8; ++c) s += __expf(t[c] - m);
  float lse = m + __logf(s);
  float4 o0 = make_float4(t[0] - lse, t[1] - lse, t[2] - lse, t[3] - lse);
  float4 o1 = make_float4(t[4] - lse, t[5] - lse, t[6] - lse, t[7] - lse);
  float4* op = (float4*)(out + (size_t)e * 8);
  op[0] = o0; op[1] = o1;
}

extern "C" void kernel_launch(void* const* d_in, const int* in_sizes, int n_in,
                              void* d_out, int out_size, void* d_ws, size_t ws_size,
                              hipStream_t stream) {
  const float* x   = (const float*)d_in[0];
  const int*   ei  = (const int*)d_in[1];
  const float* W1l = (const float*)d_in[2];
  const float* b1  = (const float*)d_in[3];
  const float* W1r = (const float*)d_in[4];
  const float* W2l = (const float*)d_in[5];
  const float* b2  = (const float*)d_in[6];
  const float* W2r = (const float*)d_in[7];
  const float* Wc  = (const float*)d_in[8];
  const float* bc  = (const float*)d_in[9];
  float* out = (float*)d_out;

  const int N = in_sizes[0] / 128;   // 100000
  const int E = in_sizes[1] / 2;     // 3200000
  const size_t N16 = (size_t)N * 16;
  const int NB = (N + BUCKET_SZ - 1) >> BUCKET_BITS;   // 196
  const int chunk = (E + NBLK - 1) / NBLK;

  // Workspace layout
  __half* yh = (__half*)d_ws;            // N*16 half
  __half* ph = yh + N16;                 // N*16 half
  __half* Uh = ph + N16;                 // N*8 half
  __half* Vh = Uh + (size_t)N * 8;       // N*8 half
  float*  z  = (float*)(Vh + (size_t)N * 8);  // N*16 f32
  float*  q  = z + N16;                  // N*16 f32
  int* counts  = (int*)(q + N16);        // NB*NBLK
  int* locoff  = counts + NB * NBLK;     // NB*NBLK
  int* total   = locoff + NB * NBLK;     // NB
  int* bstart  = total + NB;             // NB + 1
  int* elist   = bstart + NB + 1;        // E
  int* row_csr = elist + E;              // N + 1

  bincount_kernel<<<NBLK, 512, 0, stream>>>(ei, counts, E, NB, chunk);
  scan1_kernel<<<NB, 512, 0, stream>>>(counts, locoff, total);
  scan2_kernel<<<1, 256, 0, stream>>>(total, bstart, NB);
  binwrite_kernel<<<NBLK, 512, 0, stream>>>(ei, locoff, bstart, elist, E, NB, chunk);
  size_t smem = (STAGE_CAP + 512 + 16) * sizeof(int);
  sort_kernel<<<NB, 1024, smem, stream>>>(elist, bstart, row_csr, N);

  lin1_kernel<<<(N + 31) / 32, 256, 0, stream>>>(x, W1l, W1r, yh, z, N);

  int ngrid = (N * 16 + 255) / 256;
  agg1_kernel<<<ngrid, 256, 0, stream>>>(yh, z, row_csr, elist, b1, W2l, W2r, ph, q, N);
  agg2_kernel<<<ngrid, 256, 0, stream>>>(ph, q, row_csr, elist, b2, Wc, Uh, Vh, N);

  int egrid = (E + 255) / 256;
  edge_out_kernel<<<egrid, 256, 0, stream>>>(ei, Uh, Vh, bc, out, E);
}